// Round 2
// baseline (207.984 us; speedup 1.0000x reference)
//
#include <hip/hip_runtime.h>

// ---------------------------------------------------------------------------
// TensorProduct: e3nn-style channelwise tensor product
//   x1: [16384, 1152] f32  (irreps 128x0e + 128x1o + 128x2e)
//   x2: [16384, 16]   f32  (irreps 1x0e + 1x1o + 1x2e + 1x3o)
//   w : [16384, 2176] f32  (17 paths x 128 mul)
//   out:[16384, 9088] f32  (paths sorted by l3)
// ---------------------------------------------------------------------------

#define NPATH 17

// Path metadata, in PATHS enumeration order (i over in1, j over in2, l3 asc)
__device__ const int d_PL1[NPATH]  = {0,0,0,0, 1,1,1,1,1,1, 2,2,2,2,2,2,2};
__device__ const int d_PL2[NPATH]  = {0,1,2,3, 0,1,1,2,2,3, 0,1,1,2,2,3,3};
__device__ const int d_PL3[NPATH]  = {0,1,2,3, 1,0,2,1,3,2, 2,1,3,0,2,1,3};
// offsets into dense CG table (size (2l1+1)(2l2+1)(2l3+1) each)
__device__ const int d_CGOFF[NPATH] = {0,1,10,35,84,93,102,147,192,297,402,427,472,577,602,727,832};
// x2 irrep offsets per path (OFF2[j])
__device__ const int d_X2OFF[NPATH] = {0,1,4,9, 0,1,1,4,4,9, 0,1,1,4,4,9,9};
// K (x2-contracted CG) layout: per-path slabs of N1*N3 floats, padded to mult of 4
__device__ const int d_KOFF[NPATH]  = {0,4,8,16,24,36,40,56,68,92,108,136,152,188,196,224,240};
__device__ const int d_KN[NPATH]    = {1,3,5,7, 9,3,15,9,21,15, 25,15,35,5,25,15,35};

__device__ float g_cg[1077];   // dense real CG, recomputed every call (deterministic)

// ---------------- CG setup (exact port of the reference math, fp64) --------

__device__ double dfactd(int n){ double r=1.0; for(int i=2;i<=n;++i) r *= (double)i; return r; }

__device__ double su2cg(int j1,int m1,int j2,int m2,int j3,int m3){
  if (m1+m2 != m3) return 0.0;
  double pref = sqrt((double)(2*j3+1)*dfactd(j1+j2-j3)*dfactd(j1-j2+j3)*dfactd(-j1+j2+j3)/dfactd(j1+j2+j3+1));
  pref *= sqrt(dfactd(j1+m1)*dfactd(j1-m1)*dfactd(j2+m2)*dfactd(j2-m2)*dfactd(j3+m3)*dfactd(j3-m3));
  int lo = 0;
  if (j2-j3-m1 > lo) lo = j2-j3-m1;
  if (j1-j3+m2 > lo) lo = j1-j3+m2;
  int hi = j1+j2-j3;
  if (j1-m1 < hi) hi = j1-m1;
  if (j2+m2 < hi) hi = j2+m2;
  double s = 0.0;
  for (int k=lo;k<=hi;++k){
    double d = dfactd(k)*dfactd(j1+j2-j3-k)*dfactd(j1-m1-k)*dfactd(j2+m2-k)
             * dfactd(j3-j2+m1+k)*dfactd(j3-j1-m2+k);
    s += ((k&1) ? -1.0 : 1.0)/d;
  }
  return pref*s;
}

struct Cplx { double re, im; };

// nonzeros of row r of q_l (real<-complex change of basis, phased by (-i)^l)
__device__ int qrow(int l, int r, int* cols, Cplx* vals){
  const double is2 = 0.70710678118654752440;
  int mp = r - l;
  int n;
  double vr[2], vi[2];
  if (mp < 0)      { cols[0]=l-mp; vr[0]=is2;  vi[0]=0.0;  cols[1]=l+mp; vr[1]=0.0; vi[1]=-is2; n=2; }
  else if (mp==0)  { cols[0]=l;    vr[0]=1.0;  vi[0]=0.0;  n=1; }
  else { double sg = (mp&1)? -1.0 : 1.0;
         cols[0]=l+mp; vr[0]=sg*is2; vi[0]=0.0;
         cols[1]=l-mp; vr[1]=0.0;    vi[1]=sg*is2; n=2; }
  int ph = l & 3;   // multiply by (-i)^l
  for (int t=0;t<n;++t){
    double re=vr[t], im=vi[t], nr, ni;
    if      (ph==0){ nr=re;  ni=im;  }
    else if (ph==1){ nr=im;  ni=-re; }
    else if (ph==2){ nr=-re; ni=-im; }
    else           { nr=-im; ni=re;  }
    vals[t].re=nr; vals[t].im=ni;
  }
  return n;
}

__global__ void tp_cg_setup(){
  const int p = blockIdx.x;
  const int l1=d_PL1[p], l2=d_PL2[p], l3=d_PL3[p];
  const int N2=2*l2+1, N3=2*l3+1;
  const int n = (2*l1+1)*N2*N3;
  __shared__ double sre[245], sim[245];
  for (int e=threadIdx.x; e<n; e+=blockDim.x){
    int k = e % N3, rem = e / N3;
    int j = rem % N2, i = rem / N2;
    int ca[2], cb[2], cc[2];
    Cplx va[2], vb[2], vc[2];
    int na=qrow(l1,i,ca,va), nb=qrow(l2,j,cb,vb), nc=qrow(l3,k,cc,vc);
    double ar=0.0, ai=0.0;
    for (int a=0;a<na;++a) for (int b=0;b<nb;++b){
      double r1=va[a].re, i1=-va[a].im;   // conj
      double r2=vb[b].re, i2=-vb[b].im;   // conj
      double r12 = r1*r2 - i1*i2;
      double i12 = r1*i2 + i1*r2;
      for (int c=0;c<nc;++c){
        double cg = su2cg(l1, ca[a]-l1, l2, cb[b]-l2, l3, cc[c]-l3);
        if (cg != 0.0){
          double r3=vc[c].re, i3=vc[c].im;
          ar += cg*(r12*r3 - i12*i3);
          ai += cg*(r12*i3 + i12*r3);
        }
      }
    }
    sre[e]=ar; sim[e]=ai;
  }
  __syncthreads();
  __shared__ double s_scale;
  __shared__ int s_usere;
  if (threadIdx.x==0){
    double nr=0.0, ni=0.0;
    for (int e=0;e<n;++e){ nr += sre[e]*sre[e]; ni += sim[e]*sim[e]; }
    int ur = (nr >= ni) ? 1 : 0;
    s_usere = ur;
    s_scale = 1.0/sqrt(ur ? nr : ni);
  }
  __syncthreads();
  const int off = d_CGOFF[p];
  for (int e=threadIdx.x; e<n; e+=blockDim.x)
    g_cg[off+e] = (float)((s_usere ? sre[e] : sim[e]) * s_scale);
}

// ---------------- main kernel ----------------------------------------------

template<int L1, int L3>
__device__ __forceinline__ void path_out(const float* __restrict__ Kp,
                                         const float* __restrict__ xv,
                                         float wa, float* __restrict__ op){
  constexpr int N1 = 2*L1+1, N3 = 2*L3+1;
  float y[N3];
#pragma unroll
  for (int k=0;k<N3;++k) y[k] = 0.0f;
#pragma unroll
  for (int i=0;i<N1;++i){
    const float a = xv[i];
#pragma unroll
    for (int k=0;k<N3;++k) y[k] = fmaf(Kp[i*N3+k], a, y[k]);
  }
#pragma unroll
  for (int k=0;k<N3;++k) op[k] = wa*y[k];
}

__global__ __launch_bounds__(256) void tp_main(const float* __restrict__ x1,
                                               const float* __restrict__ x2,
                                               const float* __restrict__ wts,
                                               float* __restrict__ out){
  __shared__ float sK[2][276];
  const int tid = threadIdx.x;
  const int bb  = tid >> 7;          // which of the 2 batch rows in this block
  const int u   = tid & 127;
  const long long b = (long long)blockIdx.x*2 + bb;

  // phase 1: K[i,k] = sum_j C[i,j,k] * x2[b,j]   (shared by all 128 u-threads)
  {
    const float* __restrict__ x2b = x2 + b*16;
    for (int e=u; e<243; e+=128){
      int p=0, rem=e;
      while (rem >= d_KN[p]) { rem -= d_KN[p]; ++p; }
      const int N3 = 2*d_PL3[p]+1;
      const int N2 = 2*d_PL2[p]+1;
      const int i  = rem / N3;
      const float* __restrict__ C  = g_cg + d_CGOFF[p] + (i*N2)*N3 + (rem % N3);
      const float* __restrict__ xx = x2b + d_X2OFF[p];
      float acc = 0.f;
      for (int j=0;j<N2;++j) acc = fmaf(C[j*N3], xx[j], acc);
      sK[bb][d_KOFF[p] + rem] = acc;       // rem == i*N3 + k
    }
  }
  __syncthreads();

  // phase 2: per (b,u) outputs
  const float* __restrict__ x1b = x1 + b*1152;
  float xv[9];
  xv[0] = x1b[u];
#pragma unroll
  for (int t=0;t<3;++t) xv[1+t] = x1b[128 + 3*u + t];
#pragma unroll
  for (int t=0;t<5;++t) xv[4+t] = x1b[512 + 5*u + t];
  const float* __restrict__ wb  = wts + b*2176 + u;
  float* __restrict__ outb      = out + b*9088;
  const float* __restrict__ K   = sK[bb];

  const float A0=0.08838834764831845f, A1=0.15309310892394863f,
              A2=0.19764235376052372f, A3=0.23385358667337133f;

  path_out<0,0>(K+0,   xv+0, wb[0*128]*A0,  outb + 0    + u);
  path_out<0,1>(K+4,   xv+0, wb[1*128]*A1,  outb + 384  + u*3);
  path_out<0,2>(K+8,   xv+0, wb[2*128]*A2,  outb + 2304 + u*5);
  path_out<0,3>(K+16,  xv+0, wb[3*128]*A3,  outb + 5504 + u*7);
  path_out<1,1>(K+24,  xv+1, wb[4*128]*A1,  outb + 768  + u*3);
  path_out<1,0>(K+36,  xv+1, wb[5*128]*A0,  outb + 128  + u);
  path_out<1,2>(K+40,  xv+1, wb[6*128]*A2,  outb + 2944 + u*5);
  path_out<1,1>(K+56,  xv+1, wb[7*128]*A1,  outb + 1152 + u*3);
  path_out<1,3>(K+68,  xv+1, wb[8*128]*A3,  outb + 6400 + u*7);
  path_out<1,2>(K+92,  xv+1, wb[9*128]*A2,  outb + 3584 + u*5);
  path_out<2,2>(K+108, xv+4, wb[10*128]*A2, outb + 4224 + u*5);
  path_out<2,1>(K+136, xv+4, wb[11*128]*A1, outb + 1536 + u*3);
  path_out<2,3>(K+152, xv+4, wb[12*128]*A3, outb + 7296 + u*7);
  path_out<2,0>(K+188, xv+4, wb[13*128]*A0, outb + 256  + u);
  path_out<2,2>(K+196, xv+4, wb[14*128]*A2, outb + 4864 + u*5);
  path_out<2,1>(K+224, xv+4, wb[15*128]*A1, outb + 1920 + u*3);
  path_out<2,3>(K+240, xv+4, wb[16*128]*A3, outb + 8192 + u*7);
}

// ---------------- launch ----------------------------------------------------

extern "C" void kernel_launch(void* const* d_in, const int* in_sizes, int n_in,
                              void* d_out, int out_size, void* d_ws, size_t ws_size,
                              hipStream_t stream) {
  const float* x1 = (const float*)d_in[0];
  const float* x2 = (const float*)d_in[1];
  const float* w  = (const float*)d_in[2];
  float* out = (float*)d_out;
  (void)d_ws; (void)ws_size; (void)in_sizes; (void)n_in; (void)out_size;

  tp_cg_setup<<<dim3(NPATH), dim3(256), 0, stream>>>();
  tp_main<<<dim3(16384/2), dim3(256), 0, stream>>>(x1, x2, w, out);
}

// Round 3
// 188.368 us; speedup vs baseline: 1.1041x; 1.1041x over previous
//
#include <hip/hip_runtime.h>

// ---------------------------------------------------------------------------
// TensorProduct: e3nn-style channelwise tensor product
//   x1: [16384, 1152] f32  (irreps 128x0e + 128x1o + 128x2e)
//   x2: [16384, 16]   f32  (irreps 1x0e + 1x1o + 1x2e + 1x3o)
//   w : [16384, 2176] f32  (17 paths x 128 mul)
//   out:[16384, 9088] f32  (paths sorted by l3)
// ---------------------------------------------------------------------------

#define NPATH 17

// Path metadata, in PATHS enumeration order (i over in1, j over in2, l3 asc)
__device__ const int d_PL1[NPATH]  = {0,0,0,0, 1,1,1,1,1,1, 2,2,2,2,2,2,2};
__device__ const int d_PL2[NPATH]  = {0,1,2,3, 0,1,1,2,2,3, 0,1,1,2,2,3,3};
__device__ const int d_PL3[NPATH]  = {0,1,2,3, 1,0,2,1,3,2, 2,1,3,0,2,1,3};
// offsets into dense CG table (size (2l1+1)(2l2+1)(2l3+1) each)
__device__ const int d_CGOFF[NPATH] = {0,1,10,35,84,93,102,147,192,297,402,427,472,577,602,727,832};
// x2 irrep offsets per path (OFF2[j])
__device__ const int d_X2OFF[NPATH] = {0,1,4,9, 0,1,1,4,4,9, 0,1,1,4,4,9,9};
// K (x2-contracted CG) layout: per-path slabs of N1*N3 floats, padded to mult of 4
__device__ const int d_KOFF[NPATH]  = {0,4,8,16,24,36,40,56,68,92,108,136,152,188,196,224,240};
__device__ const int d_KN[NPATH]    = {1,3,5,7, 9,3,15,9,21,15, 25,15,35,5,25,15,35};

__device__ float g_cg[1077];   // dense real CG, recomputed every call (deterministic)

// ---------------- CG setup (exact port of the reference math, fp64) --------

__device__ double dfactd(int n){ double r=1.0; for(int i=2;i<=n;++i) r *= (double)i; return r; }

__device__ double su2cg(int j1,int m1,int j2,int m2,int j3,int m3){
  if (m1+m2 != m3) return 0.0;
  double pref = sqrt((double)(2*j3+1)*dfactd(j1+j2-j3)*dfactd(j1-j2+j3)*dfactd(-j1+j2+j3)/dfactd(j1+j2+j3+1));
  pref *= sqrt(dfactd(j1+m1)*dfactd(j1-m1)*dfactd(j2+m2)*dfactd(j2-m2)*dfactd(j3+m3)*dfactd(j3-m3));
  int lo = 0;
  if (j2-j3-m1 > lo) lo = j2-j3-m1;
  if (j1-j3+m2 > lo) lo = j1-j3+m2;
  int hi = j1+j2-j3;
  if (j1-m1 < hi) hi = j1-m1;
  if (j2+m2 < hi) hi = j2+m2;
  double s = 0.0;
  for (int k=lo;k<=hi;++k){
    double d = dfactd(k)*dfactd(j1+j2-j3-k)*dfactd(j1-m1-k)*dfactd(j2+m2-k)
             * dfactd(j3-j2+m1+k)*dfactd(j3-j1-m2+k);
    s += ((k&1) ? -1.0 : 1.0)/d;
  }
  return pref*s;
}

struct Cplx { double re, im; };

// nonzeros of row r of q_l (real<-complex change of basis, phased by (-i)^l)
__device__ int qrow(int l, int r, int* cols, Cplx* vals){
  const double is2 = 0.70710678118654752440;
  int mp = r - l;
  int n;
  double vr[2], vi[2];
  if (mp < 0)      { cols[0]=l-mp; vr[0]=is2;  vi[0]=0.0;  cols[1]=l+mp; vr[1]=0.0; vi[1]=-is2; n=2; }
  else if (mp==0)  { cols[0]=l;    vr[0]=1.0;  vi[0]=0.0;  n=1; }
  else { double sg = (mp&1)? -1.0 : 1.0;
         cols[0]=l+mp; vr[0]=sg*is2; vi[0]=0.0;
         cols[1]=l-mp; vr[1]=0.0;    vi[1]=sg*is2; n=2; }
  int ph = l & 3;   // multiply by (-i)^l
  for (int t=0;t<n;++t){
    double re=vr[t], im=vi[t], nr, ni;
    if      (ph==0){ nr=re;  ni=im;  }
    else if (ph==1){ nr=im;  ni=-re; }
    else if (ph==2){ nr=-re; ni=-im; }
    else           { nr=-im; ni=re;  }
    vals[t].re=nr; vals[t].im=ni;
  }
  return n;
}

__global__ void tp_cg_setup(){
  const int p = blockIdx.x;
  const int l1=d_PL1[p], l2=d_PL2[p], l3=d_PL3[p];
  const int N2=2*l2+1, N3=2*l3+1;
  const int n = (2*l1+1)*N2*N3;
  __shared__ double sre[245], sim[245];
  for (int e=threadIdx.x; e<n; e+=blockDim.x){
    int k = e % N3, rem = e / N3;
    int j = rem % N2, i = rem / N2;
    int ca[2], cb[2], cc[2];
    Cplx va[2], vb[2], vc[2];
    int na=qrow(l1,i,ca,va), nb=qrow(l2,j,cb,vb), nc=qrow(l3,k,cc,vc);
    double ar=0.0, ai=0.0;
    for (int a=0;a<na;++a) for (int b=0;b<nb;++b){
      double r1=va[a].re, i1=-va[a].im;   // conj
      double r2=vb[b].re, i2=-vb[b].im;   // conj
      double r12 = r1*r2 - i1*i2;
      double i12 = r1*i2 + i1*r2;
      for (int c=0;c<nc;++c){
        double cg = su2cg(l1, ca[a]-l1, l2, cb[b]-l2, l3, cc[c]-l3);
        if (cg != 0.0){
          double r3=vc[c].re, i3=vc[c].im;
          ar += cg*(r12*r3 - i12*i3);
          ai += cg*(r12*i3 + i12*r3);
        }
      }
    }
    sre[e]=ar; sim[e]=ai;
  }
  __syncthreads();
  __shared__ double s_scale;
  __shared__ int s_usere;
  if (threadIdx.x==0){
    double nr=0.0, ni=0.0;
    for (int e=0;e<n;++e){ nr += sre[e]*sre[e]; ni += sim[e]*sim[e]; }
    int ur = (nr >= ni) ? 1 : 0;
    s_usere = ur;
    s_scale = 1.0/sqrt(ur ? nr : ni);
  }
  __syncthreads();
  const int off = d_CGOFF[p];
  for (int e=threadIdx.x; e<n; e+=blockDim.x)
    g_cg[off+e] = (float)((s_usere ? sre[e] : sim[e]) * s_scale);
}

// ---------------- main kernel ----------------------------------------------

template<int L1, int L3>
__device__ __forceinline__ void path_out(const float* __restrict__ Kp,
                                         const float* __restrict__ xv,
                                         float wa, float* __restrict__ op){
  constexpr int N1 = 2*L1+1, N3 = 2*L3+1;
  float y[N3];
#pragma unroll
  for (int k=0;k<N3;++k) y[k] = 0.0f;
#pragma unroll
  for (int i=0;i<N1;++i){
    const float a = xv[i];
#pragma unroll
    for (int k=0;k<N3;++k) y[k] = fmaf(Kp[i*N3+k], a, y[k]);
  }
#pragma unroll
  for (int k=0;k<N3;++k) op[k] = wa*y[k];
}

__global__ __launch_bounds__(256) void tp_main(const float* __restrict__ x1,
                                               const float* __restrict__ x2,
                                               const float* __restrict__ wts,
                                               float* __restrict__ out){
  __shared__ float sK[276];
  __shared__ __align__(16) float sOut[9088];
  const int tid = threadIdx.x;
  const int t   = tid >> 7;          // path-half
  const int u   = tid & 127;
  const long long b = blockIdx.x;

  // phase 1: K[i,k] = sum_j C[i,j,k] * x2[b,j]  (243 values, one per thread)
  if (tid < 243){
    const float* __restrict__ x2b = x2 + b*16;
    int p=0, rem=tid;
    while (rem >= d_KN[p]) { rem -= d_KN[p]; ++p; }
    const int N3 = 2*d_PL3[p]+1;
    const int N2 = 2*d_PL2[p]+1;
    const int i  = rem / N3;
    const float* __restrict__ C  = g_cg + d_CGOFF[p] + (i*N2)*N3 + (rem % N3);
    const float* __restrict__ xx = x2b + d_X2OFF[p];
    float acc = 0.f;
    for (int j=0;j<N2;++j) acc = fmaf(C[j*N3], xx[j], acc);
    sK[d_KOFF[p] + rem] = acc;       // rem == i*N3 + k
  }
  __syncthreads();

  // phase 2: per (b,u) path outputs into the LDS row buffer.
  // t=0 handles l1 in {0,1} paths (p0..p9), t=1 handles l1=2 paths (p10..p16).
  {
    const float* __restrict__ x1b = x1 + b*1152;
    const float* __restrict__ wb  = wts + b*2176 + u;
    const float* __restrict__ K   = sK;

    const float A0=0.08838834764831845f, A1=0.15309310892394863f,
                A2=0.19764235376052372f, A3=0.23385358667337133f;

    if (t == 0){
      float xv[4];
      xv[0] = x1b[u];
#pragma unroll
      for (int q=0;q<3;++q) xv[1+q] = x1b[128 + 3*u + q];
      path_out<0,0>(K+0,   xv+0, wb[0*128]*A0,  sOut + 0    + u);
      path_out<0,1>(K+4,   xv+0, wb[1*128]*A1,  sOut + 384  + u*3);
      path_out<0,2>(K+8,   xv+0, wb[2*128]*A2,  sOut + 2304 + u*5);
      path_out<0,3>(K+16,  xv+0, wb[3*128]*A3,  sOut + 5504 + u*7);
      path_out<1,1>(K+24,  xv+1, wb[4*128]*A1,  sOut + 768  + u*3);
      path_out<1,0>(K+36,  xv+1, wb[5*128]*A0,  sOut + 128  + u);
      path_out<1,2>(K+40,  xv+1, wb[6*128]*A2,  sOut + 2944 + u*5);
      path_out<1,1>(K+56,  xv+1, wb[7*128]*A1,  sOut + 1152 + u*3);
      path_out<1,3>(K+68,  xv+1, wb[8*128]*A3,  sOut + 6400 + u*7);
      path_out<1,2>(K+92,  xv+1, wb[9*128]*A2,  sOut + 3584 + u*5);
    } else {
      float xv[5];
#pragma unroll
      for (int q=0;q<5;++q) xv[q] = x1b[512 + 5*u + q];
      path_out<2,2>(K+108, xv, wb[10*128]*A2, sOut + 4224 + u*5);
      path_out<2,1>(K+136, xv, wb[11*128]*A1, sOut + 1536 + u*3);
      path_out<2,3>(K+152, xv, wb[12*128]*A3, sOut + 7296 + u*7);
      path_out<2,0>(K+188, xv, wb[13*128]*A0, sOut + 256  + u);
      path_out<2,2>(K+196, xv, wb[14*128]*A2, sOut + 4864 + u*5);
      path_out<2,1>(K+224, xv, wb[15*128]*A1, sOut + 1920 + u*3);
      path_out<2,3>(K+240, xv, wb[16*128]*A3, sOut + 8192 + u*7);
    }
  }
  __syncthreads();

  // phase 3: coalesced float4 flush of the whole row (9088 floats = 2272 x f4)
  {
    float4* __restrict__ dst = (float4*)(out + b*9088);
    const float4* __restrict__ src = (const float4*)sOut;
    for (int idx = tid; idx < 2272; idx += 256)
      dst[idx] = src[idx];
  }
}

// ---------------- launch ----------------------------------------------------

extern "C" void kernel_launch(void* const* d_in, const int* in_sizes, int n_in,
                              void* d_out, int out_size, void* d_ws, size_t ws_size,
                              hipStream_t stream) {
  const float* x1 = (const float*)d_in[0];
  const float* x2 = (const float*)d_in[1];
  const float* w  = (const float*)d_in[2];
  float* out = (float*)d_out;
  (void)d_ws; (void)ws_size; (void)in_sizes; (void)n_in; (void)out_size;

  tp_cg_setup<<<dim3(NPATH), dim3(256), 0, stream>>>();
  tp_main<<<dim3(16384), dim3(256), 0, stream>>>(x1, x2, w, out);
}

// Round 4
// 167.155 us; speedup vs baseline: 1.2443x; 1.1269x over previous
//
#include <hip/hip_runtime.h>

// ---------------------------------------------------------------------------
// TensorProduct: e3nn-style channelwise tensor product
//   x1: [16384, 1152] f32  (irreps 128x0e + 128x1o + 128x2e)
//   x2: [16384, 16]   f32  (irreps 1x0e + 1x1o + 1x2e + 1x3o)
//   w : [16384, 2176] f32  (17 paths x 128 mul)
//   out:[16384, 9088] f32  (paths sorted by l3)
// CG coefficients are generated entirely at COMPILE TIME (constexpr fp64
// port of the reference Racah + complex->real basis-change math).
// ---------------------------------------------------------------------------

#define NPATH 17

namespace cgc {

constexpr double FT[16] = {1.,1.,2.,6.,24.,120.,720.,5040.,40320.,362880.,
  3628800.,39916800.,479001600.,6227020800.,87178291200.,1307674368000.};

constexpr double csqrt(double x){
  if (x <= 0.0) return 0.0;
  double g = x > 1.0 ? x : 1.0;
  for (int i=0;i<48;++i) g = 0.5*(g + x/g);
  return g;
}

constexpr double su2cg(int j1,int m1,int j2,int m2,int j3,int m3){
  if (m1+m2 != m3) return 0.0;
  double pref = csqrt((double)(2*j3+1)*FT[j1+j2-j3]*FT[j1-j2+j3]*FT[-j1+j2+j3]/FT[j1+j2+j3+1]);
  pref *= csqrt(FT[j1+m1]*FT[j1-m1]*FT[j2+m2]*FT[j2-m2]*FT[j3+m3]*FT[j3-m3]);
  int lo=0; if (j2-j3-m1>lo) lo=j2-j3-m1; if (j1-j3+m2>lo) lo=j1-j3+m2;
  int hi=j1+j2-j3; if (j1-m1<hi) hi=j1-m1; if (j2+m2<hi) hi=j2+m2;
  double s=0.0;
  for (int k=lo;k<=hi;++k){
    double d = FT[k]*FT[j1+j2-j3-k]*FT[j1-m1-k]*FT[j2+m2-k]*FT[j3-j2+m1+k]*FT[j3-j1-m2+k];
    s += ((k&1)? -1.0:1.0)/d;
  }
  return pref*s;
}

// q-row nonzeros of real<-complex change of basis (e3nn, phased by (-i)^l)
constexpr int qrow(int l, int r, int* cols, double* vr, double* vi){
  const double is2 = 0.70710678118654752440;
  int mp = r - l;
  int n = 0;
  double tr[2]={0,0}, ti[2]={0,0};
  if (mp < 0){ cols[0]=l-mp; tr[0]=is2; ti[0]=0.0; cols[1]=l+mp; tr[1]=0.0; ti[1]=-is2; n=2; }
  else if (mp==0){ cols[0]=l; tr[0]=1.0; ti[0]=0.0; n=1; }
  else { double sg=(mp&1)?-1.0:1.0; cols[0]=l+mp; tr[0]=sg*is2; ti[0]=0.0;
         cols[1]=l-mp; tr[1]=0.0; ti[1]=sg*is2; n=2; }
  int ph = l & 3;   // multiply by (-i)^l
  for (int t=0;t<n;++t){
    double re=tr[t], im=ti[t], nr=0, ni=0;
    if (ph==0){ nr=re; ni=im; } else if (ph==1){ nr=im; ni=-re; }
    else if (ph==2){ nr=-re; ni=-im; } else { nr=-im; ni=re; }
    vr[t]=nr; vi[t]=ni;
  }
  return n;
}

constexpr int PL1[NPATH] = {0,0,0,0, 1,1,1,1,1,1, 2,2,2,2,2,2,2};
constexpr int PL2[NPATH] = {0,1,2,3, 0,1,1,2,2,3, 0,1,1,2,2,3,3};
constexpr int PL3[NPATH] = {0,1,2,3, 1,0,2,1,3,2, 2,1,3,0,2,1,3};
constexpr int CGOFF[NPATH] = {0,1,10,35,84,93,102,147,192,297,402,427,472,577,602,727,832};
constexpr int X2OFF[NPATH] = {0,1,4,9, 0,1,1,4,4,9, 0,1,1,4,4,9,9};
constexpr int KOFF[NPATH]  = {0,4,8,16,24,36,40,56,68,92,108,136,152,188,196,224,240};
constexpr int KN[NPATH]    = {1,3,5,7, 9,3,15,9,21,15, 25,15,35,5,25,15,35};

struct CGTab { float v[1077]; };

constexpr CGTab make_cg(){
  CGTab R{};
  for (int p=0;p<NPATH;++p){
    const int l1=PL1[p], l2=PL2[p], l3=PL3[p];
    const int N1=2*l1+1, N2=2*l2+1, N3=2*l3+1;
    // dense complex-basis CG, cached (243 su2cg evaluations total)
    double cc[245] = {};
    for (int a=0;a<N1;++a) for (int b=0;b<N2;++b){
      int m1=a-l1, m2=b-l2, m3=m1+m2;
      if (m3>=-l3 && m3<=l3)
        cc[(a*N2+b)*N3 + (m3+l3)] = su2cg(l1,m1,l2,m2,l3,m3);
    }
    double re[245]={}, im[245]={};
    for (int i=0;i<N1;++i){
      int ca[2]={}; double ar[2]={}, ai[2]={};
      const int na=qrow(l1,i,ca,ar,ai);
      for (int j=0;j<N2;++j){
        int cb[2]={}; double br[2]={}, bi[2]={};
        const int nb=qrow(l2,j,cb,br,bi);
        for (int k=0;k<N3;++k){
          int cd[2]={}; double dr[2]={}, di[2]={};
          const int nd=qrow(l3,k,cd,dr,di);
          double sr=0, si=0;
          for (int x=0;x<na;++x) for (int y=0;y<nb;++y){
            const double r1=ar[x], i1=-ai[x];   // conj
            const double r2=br[y], i2=-bi[y];   // conj
            const double r12 = r1*r2 - i1*i2;
            const double i12 = r1*i2 + i1*r2;
            for (int z=0;z<nd;++z){
              const double cg = cc[(ca[x]*N2+cb[y])*N3 + cd[z]];
              if (cg != 0.0){
                sr += cg*(r12*dr[z] - i12*di[z]);
                si += cg*(r12*di[z] + i12*dr[z]);
              }
            }
          }
          re[(i*N2+j)*N3+k]=sr; im[(i*N2+j)*N3+k]=si;
        }
      }
    }
    const int n = N1*N2*N3;
    double nr=0, ni=0;
    for (int e=0;e<n;++e){ nr += re[e]*re[e]; ni += im[e]*im[e]; }
    const bool usere = (nr >= ni);
    const double sc = 1.0 / csqrt(usere ? nr : ni);
    for (int e=0;e<n;++e)
      R.v[CGOFF[p]+e] = (float)((usere ? re[e] : im[e]) * sc);
  }
  return R;
}

// per-thread descriptor for the K (= C . x2) contraction, 243 entries
struct EMap { unsigned short cgbase, dst; unsigned char stride, cnt, x2off, pad; };
struct EMaps { EMap m[243]; };
constexpr EMaps make_emaps(){
  EMaps M{};
  int e=0;
  for (int p=0;p<NPATH;++p){
    const int l2=PL2[p], l3=PL3[p];
    const int N2=2*l2+1, N3=2*l3+1;
    for (int rem=0; rem<KN[p]; ++rem, ++e){
      const int i = rem / N3, k = rem % N3;
      M.m[e].cgbase = (unsigned short)(CGOFF[p] + i*N2*N3 + k);
      M.m[e].dst    = (unsigned short)(KOFF[p] + rem);
      M.m[e].stride = (unsigned char)N3;
      M.m[e].cnt    = (unsigned char)N2;
      M.m[e].x2off  = (unsigned char)X2OFF[p];
      M.m[e].pad    = 0;
    }
  }
  return M;
}

} // namespace cgc

__device__ __constant__ cgc::CGTab c_cg  = cgc::make_cg();
__device__ __constant__ cgc::EMaps c_map = cgc::make_emaps();

// ---------------- main kernel ----------------------------------------------

template<int L1, int L3>
__device__ __forceinline__ void path_out(const float* __restrict__ Kp,
                                         const float* __restrict__ xv,
                                         float wa, float* __restrict__ op){
  constexpr int N1 = 2*L1+1, N3 = 2*L3+1;
  float y[N3];
#pragma unroll
  for (int k=0;k<N3;++k) y[k] = 0.0f;
#pragma unroll
  for (int i=0;i<N1;++i){
    const float a = xv[i];
#pragma unroll
    for (int k=0;k<N3;++k) y[k] = fmaf(Kp[i*N3+k], a, y[k]);
  }
#pragma unroll
  for (int k=0;k<N3;++k) op[k] = wa*y[k];
}

__global__ __launch_bounds__(256) void tp_main(const float* __restrict__ x1,
                                               const float* __restrict__ x2,
                                               const float* __restrict__ wts,
                                               float* __restrict__ out){
  __shared__ float sK[276];
  __shared__ __align__(16) float sOut[9088];
  const int tid = threadIdx.x;
  const int t   = tid >> 7;          // path-half
  const int u   = tid & 127;
  const long long b = blockIdx.x;

  // phase 1: K[i,k] = sum_j C[i,j,k] * x2[b,j]  (243 values, one per thread)
  if (tid < 243){
    const cgc::EMap m = c_map.m[tid];
    const float* __restrict__ C  = c_cg.v + m.cgbase;
    const float* __restrict__ xx = x2 + b*16 + m.x2off;
    float acc = 0.f;
    for (int j=0;j<m.cnt;++j) acc = fmaf(C[j*m.stride], xx[j], acc);
    sK[m.dst] = acc;
  }
  __syncthreads();

  // phase 2: per (b,u) path outputs into the LDS row buffer.
  // Balanced split: t0 = p0..p9 + p13 + p14 (118 fma / 46 writes),
  //                 t1 = p10,p11,p12,p15,p16 (125 fma / 25 writes).
  {
    const float* __restrict__ x1b = x1 + b*1152;
    const float* __restrict__ wb  = wts + b*2176 + u;
    const float* __restrict__ K   = sK;

    const float A0=0.08838834764831845f, A1=0.15309310892394863f,
                A2=0.19764235376052372f, A3=0.23385358667337133f;

    if (t == 0){
      float xa[4];
      xa[0] = x1b[u];
#pragma unroll
      for (int q=0;q<3;++q) xa[1+q] = x1b[128 + 3*u + q];
      float xc[5];
#pragma unroll
      for (int q=0;q<5;++q) xc[q] = x1b[512 + 5*u + q];
      path_out<0,0>(K+0,   xa,   wb[0*128]*A0,  sOut + 0    + u);
      path_out<0,1>(K+4,   xa,   wb[1*128]*A1,  sOut + 384  + u*3);
      path_out<0,2>(K+8,   xa,   wb[2*128]*A2,  sOut + 2304 + u*5);
      path_out<0,3>(K+16,  xa,   wb[3*128]*A3,  sOut + 5504 + u*7);
      path_out<1,1>(K+24,  xa+1, wb[4*128]*A1,  sOut + 768  + u*3);
      path_out<1,0>(K+36,  xa+1, wb[5*128]*A0,  sOut + 128  + u);
      path_out<1,2>(K+40,  xa+1, wb[6*128]*A2,  sOut + 2944 + u*5);
      path_out<1,1>(K+56,  xa+1, wb[7*128]*A1,  sOut + 1152 + u*3);
      path_out<1,3>(K+68,  xa+1, wb[8*128]*A3,  sOut + 6400 + u*7);
      path_out<1,2>(K+92,  xa+1, wb[9*128]*A2,  sOut + 3584 + u*5);
      path_out<2,0>(K+188, xc,   wb[13*128]*A0, sOut + 256  + u);
      path_out<2,2>(K+196, xc,   wb[14*128]*A2, sOut + 4864 + u*5);
    } else {
      float xc[5];
#pragma unroll
      for (int q=0;q<5;++q) xc[q] = x1b[512 + 5*u + q];
      path_out<2,2>(K+108, xc, wb[10*128]*A2, sOut + 4224 + u*5);
      path_out<2,1>(K+136, xc, wb[11*128]*A1, sOut + 1536 + u*3);
      path_out<2,3>(K+152, xc, wb[12*128]*A3, sOut + 7296 + u*7);
      path_out<2,1>(K+224, xc, wb[15*128]*A1, sOut + 1920 + u*3);
      path_out<2,3>(K+240, xc, wb[16*128]*A3, sOut + 8192 + u*7);
    }
  }
  __syncthreads();

  // phase 3: coalesced float4 flush of the whole row (9088 floats = 2272 x f4)
  {
    float4* __restrict__ dst = (float4*)(out + b*9088);
    const float4* __restrict__ src = (const float4*)sOut;
    for (int idx = tid; idx < 2272; idx += 256)
      dst[idx] = src[idx];
  }
}

// ---------------- launch ----------------------------------------------------

extern "C" void kernel_launch(void* const* d_in, const int* in_sizes, int n_in,
                              void* d_out, int out_size, void* d_ws, size_t ws_size,
                              hipStream_t stream) {
  const float* x1 = (const float*)d_in[0];
  const float* x2 = (const float*)d_in[1];
  const float* w  = (const float*)d_in[2];
  float* out = (float*)d_out;
  (void)d_ws; (void)ws_size; (void)in_sizes; (void)n_in; (void)out_size;

  tp_main<<<dim3(16384), dim3(256), 0, stream>>>(x1, x2, w, out);
}